// Round 10
// baseline (47.823 us; speedup 1.0000x reference)
//
#include <hip/hip_runtime.h>

// Problem constants: B=128, N=1024, D=8, S=64
constexpr int B   = 128;
constexpr int N   = 1024;
constexpr int DS  = 512;            // D*S, contiguous innermost per (b,n)
constexpr int NC  = 32;             // n-chunk per block (R10: 16 -> 32, 64 KB runs/wave)
constexpr int NCH = N / NC;         // 32 chunks
constexpr int BQ  = 4;              // b's per block (one per wave)
constexpr int NBQ = B / BQ;         // 32 b-quads

typedef float f32x4 __attribute__((ext_vector_type(4)));

// R10 = R9 with NC=32: each wave streams 64 KB of x CONTIGUOUSLY (32 n of one
// b). W tile 64 KB LDS -> 2 blocks/CU, 8 waves/CU (VGPR ~100-130 < 256 cap).
// Contiguity ladder so far: 2KB->16KB +4% (R3), 16->32KB +2.5% (R9).
// Joint reduce-scatter extended to 32 values (validated recursion, 5 stages;
// lane l<32 owns j = 16b0+8b1+4b2+2b3+b4). Lessons kept: no fences (R6), no
// fused handshake (R7), plain stores + kernel boundary (R1-R3, R8).
__global__ __launch_bounds__(256) void mpjrd_spike_kernel(
    const float* __restrict__ x,       // [B,N,DS]
    const float* __restrict__ W,       // [N,DS]
    const float* __restrict__ theta,   // [N]
    float*       __restrict__ out,     // spikes[B,N] | rates[N] | thetas[N] | r_hats[N]
    float*       __restrict__ partial) // ws: [NBQ][N]
{
    __shared__ float Wl[NC * DS];      // 64 KB W tile
    __shared__ float thl[NC];
    __shared__ float s_cnt[BQ][NC];

    const int tid  = threadIdx.x;
    const int lane = tid & 63;
    const int g    = tid >> 6;                 // wave in block = b within quad
    const int nc   = blockIdx.x & (NCH - 1);
    const int bq   = blockIdx.x >> 5;          // blockIdx / NCH
    const int n0   = nc * NC;
    const int b    = bq * BQ + g;

    // Stage W tile: 16384 floats = 4096 float4, 16 per thread, coalesced.
    {
        const f32x4* Wg = reinterpret_cast<const f32x4*>(W + (size_t)n0 * DS);
        f32x4* Wd = reinterpret_cast<f32x4*>(Wl);
        #pragma unroll
        for (int r = 0; r < 16; ++r) Wd[tid + r * 256] = Wg[tid + r * 256];
        if (tid < NC) thl[tid] = theta[n0 + tid];
    }
    __syncthreads();

    const float* xp0 = x + ((size_t)b * N + n0) * DS + (size_t)lane * 4;

    // 32 per-lane fp64 partial dots; no cross-lane ops in the streaming loop.
    double a[NC];
    #pragma unroll
    for (int j = 0; j < NC; ++j) {
        const float* xp = xp0 + (size_t)j * DS;
        const f32x4 x0 = __builtin_nontemporal_load(reinterpret_cast<const f32x4*>(xp));
        const f32x4 x1 = __builtin_nontemporal_load(reinterpret_cast<const f32x4*>(xp + 256));
        const f32x4 wa = *reinterpret_cast<const f32x4*>(Wl + j * DS + lane * 4);
        const f32x4 wb = *reinterpret_cast<const f32x4*>(Wl + j * DS + lane * 4 + 256);
        // fp64 accumulation: fp32*fp32 exact in fp64 -> threshold decisions
        // bit-stable vs the numpy reference (spikes absmax 0.0 in R1-R9).
        double p0 = (double)x0.x * (double)wa.x;
        p0 += (double)x0.y * (double)wa.y;
        p0 += (double)x0.z * (double)wa.z;
        p0 += (double)x0.w * (double)wa.w;
        double p1 = (double)x1.x * (double)wb.x;
        p1 += (double)x1.y * (double)wb.y;
        p1 += (double)x1.z * (double)wb.z;
        p1 += (double)x1.w * (double)wb.w;
        a[j] = p0 + p1;
    }

    // Joint reduce-scatter: 64 lanes x 32 values -> lane (l&31) owns
    // j = 16*(l&1) + 8*((l>>1)&1) + 4*((l>>2)&1) + 2*((l>>3)&1) + ((l>>4)&1).
    const bool h1 = lane & 1;
    double r1[16];
    #pragma unroll
    for (int k = 0; k < 16; ++k)
        r1[k] = (h1 ? a[k + 16] : a[k]) + __shfl_xor(h1 ? a[k] : a[k + 16], 1);
    const bool h2 = lane & 2;
    double r2[8];
    #pragma unroll
    for (int k = 0; k < 8; ++k)
        r2[k] = (h2 ? r1[k + 8] : r1[k]) + __shfl_xor(h2 ? r1[k] : r1[k + 8], 2);
    const bool h4 = lane & 4;
    double r3[4];
    #pragma unroll
    for (int k = 0; k < 4; ++k)
        r3[k] = (h4 ? r2[k + 4] : r2[k]) + __shfl_xor(h4 ? r2[k] : r2[k + 4], 4);
    const bool h8 = lane & 8;
    double r4[2];
    #pragma unroll
    for (int k = 0; k < 2; ++k)
        r4[k] = (h8 ? r3[k + 2] : r3[k]) + __shfl_xor(h8 ? r3[k] : r3[k + 2], 8);
    const bool h16 = lane & 16;
    double e = (h16 ? r4[1] : r4[0]) + __shfl_xor(h16 ? r4[0] : r4[1], 16);
    e += __shfl_xor(e, 32);

    const int j = 16 * (lane & 1) + 8 * ((lane >> 1) & 1) + 4 * ((lane >> 2) & 1) +
                  2 * ((lane >> 3) & 1) + ((lane >> 4) & 1);
    if (lane < NC) {
        const float s = (e >= (double)thl[j]) ? 1.0f : 0.0f;
        out[(size_t)b * N + n0 + j] = s;   // 32 dwords in 128 B: one transaction
        s_cnt[g][j] = s;
    }
    __syncthreads();
    if (tid < NC) {
        // Plain store; visibility to k2 guaranteed by the kernel boundary.
        partial[(size_t)bq * N + n0 + tid] =
            s_cnt[0][tid] + s_cnt[1][tid] + s_cnt[2][tid] + s_cnt[3][tid];
    }
}

// Kernel 2: thread per neuron; sum 32 quad-partials (coalesced), emit epilogue.
__global__ __launch_bounds__(256) void mpjrd_finalize_kernel(
    const float* __restrict__ partial,
    const float* __restrict__ theta,
    const float* __restrict__ r_hat,
    float*       __restrict__ out)
{
    const int n = blockIdx.x * 256 + threadIdx.x;
    float c = 0.0f;
    #pragma unroll
    for (int i = 0; i < NBQ; ++i) c += partial[(size_t)i * N + n];
    const float rate = c * (1.0f / 128.0f);
    const float rh   = 0.95f * r_hat[n] + 0.05f * rate;  // (1-ALPHA)*r_hat + ALPHA*rate
    const float th   = theta[n] + 0.1f * (rh - 0.1f);    // theta + THETA_LR*(rh - R_TARGET)
    out[(size_t)B * N + n]         = rate;
    out[(size_t)B * N + N + n]     = th;
    out[(size_t)B * N + 2 * N + n] = rh;
}

extern "C" void kernel_launch(void* const* d_in, const int* in_sizes, int n_in,
                              void* d_out, int out_size, void* d_ws, size_t ws_size,
                              hipStream_t stream) {
    const float* x     = (const float*)d_in[0];
    const float* W     = (const float*)d_in[1];
    const float* theta = (const float*)d_in[2];
    const float* r_hat = (const float*)d_in[3];
    float* out     = (float*)d_out;
    float* partial = (float*)d_ws;   // NBQ*N floats = 128 KB, fully written each call

    mpjrd_spike_kernel<<<NBQ * NCH, 256, 0, stream>>>(x, W, theta, out, partial);
    mpjrd_finalize_kernel<<<N / 256, 256, 0, stream>>>(partial, theta, r_hat, out);
}

// Round 11
// 46.559 us; speedup vs baseline: 1.0271x; 1.0271x over previous
//
#include <hip/hip_runtime.h>

// Problem constants: B=128, N=1024, D=8, S=64
constexpr int B   = 128;
constexpr int N   = 1024;
constexpr int DS  = 512;            // D*S, contiguous innermost per (b,n)
constexpr int NC  = 16;             // n-chunk per block (R9 optimum: 32 KB runs/wave)
constexpr int NCH = N / NC;         // 64 chunks
constexpr int BQ  = 8;              // b's per block (one per wave; R11: 4 -> 8)
constexpr int NBQ = B / BQ;         // 16 b-groups

typedef float f32x4 __attribute__((ext_vector_type(4)));

// R11 = R9 (the measured optimum: NC=16, 32 KB contiguous runs/wave) with
// BQ=8: 512-thread blocks so one 32 KB W tile serves 8 b's instead of 4
// (halved staging traffic; up to 2x waves/CU if LDS-limited rather than
// VGPR-limited). Contiguity ladder (measured): 2->16KB +4%, 16->32KB +2.5%,
// 32->64KB -4.5% (VGPR/occupancy cliff). Lessons kept: no fences (R6), no
// fused handshake (R7), plain stores + kernel boundary (R1-R3, R8).
__global__ __launch_bounds__(512) void mpjrd_spike_kernel(
    const float* __restrict__ x,       // [B,N,DS]
    const float* __restrict__ W,       // [N,DS]
    const float* __restrict__ theta,   // [N]
    float*       __restrict__ out,     // spikes[B,N] | rates[N] | thetas[N] | r_hats[N]
    float*       __restrict__ partial) // ws: [NBQ][N]
{
    __shared__ float Wl[NC * DS];      // 32 KB W tile
    __shared__ float thl[NC];
    __shared__ float s_cnt[BQ][NC];

    const int tid  = threadIdx.x;
    const int lane = tid & 63;
    const int g    = tid >> 6;                 // wave in block = b within group
    const int nc   = blockIdx.x & (NCH - 1);
    const int bq   = blockIdx.x >> 6;          // blockIdx / NCH
    const int n0   = nc * NC;
    const int b    = bq * BQ + g;

    // Stage W tile: 8192 floats = 2048 float4, 4 per thread, coalesced.
    {
        const f32x4* Wg = reinterpret_cast<const f32x4*>(W + (size_t)n0 * DS);
        f32x4* Wd = reinterpret_cast<f32x4*>(Wl);
        #pragma unroll
        for (int r = 0; r < 4; ++r) Wd[tid + r * 512] = Wg[tid + r * 512];
        if (tid < NC) thl[tid] = theta[n0 + tid];
    }
    __syncthreads();

    const float* xp0 = x + ((size_t)b * N + n0) * DS + (size_t)lane * 4;

    // 16 per-lane fp64 partial dots; no cross-lane ops in the streaming loop.
    double a[NC];
    #pragma unroll
    for (int j = 0; j < NC; ++j) {
        const float* xp = xp0 + (size_t)j * DS;
        const f32x4 x0 = __builtin_nontemporal_load(reinterpret_cast<const f32x4*>(xp));
        const f32x4 x1 = __builtin_nontemporal_load(reinterpret_cast<const f32x4*>(xp + 256));
        const f32x4 wa = *reinterpret_cast<const f32x4*>(Wl + j * DS + lane * 4);
        const f32x4 wb = *reinterpret_cast<const f32x4*>(Wl + j * DS + lane * 4 + 256);
        // fp64 accumulation: fp32*fp32 exact in fp64 -> threshold decisions
        // bit-stable vs the numpy reference (spikes absmax 0.0 in R1-R10).
        double p0 = (double)x0.x * (double)wa.x;
        p0 += (double)x0.y * (double)wa.y;
        p0 += (double)x0.z * (double)wa.z;
        p0 += (double)x0.w * (double)wa.w;
        double p1 = (double)x1.x * (double)wb.x;
        p1 += (double)x1.y * (double)wb.y;
        p1 += (double)x1.z * (double)wb.z;
        p1 += (double)x1.w * (double)wb.w;
        a[j] = p0 + p1;
    }

    // Joint reduce-scatter: 64 lanes x 16 values -> lane (l&15) owns
    // j = 8*(l&1) + 4*((l>>1)&1) + 2*((l>>2)&1) + ((l>>3)&1).
    const bool h1 = lane & 1;
    double r1[8];
    #pragma unroll
    for (int k = 0; k < 8; ++k)
        r1[k] = (h1 ? a[k + 8] : a[k]) + __shfl_xor(h1 ? a[k] : a[k + 8], 1);
    const bool h2 = lane & 2;
    double r2[4];
    #pragma unroll
    for (int k = 0; k < 4; ++k)
        r2[k] = (h2 ? r1[k + 4] : r1[k]) + __shfl_xor(h2 ? r1[k] : r1[k + 4], 2);
    const bool h4 = lane & 4;
    double r3[2];
    #pragma unroll
    for (int k = 0; k < 2; ++k)
        r3[k] = (h4 ? r2[k + 2] : r2[k]) + __shfl_xor(h4 ? r2[k] : r2[k + 2], 4);
    const bool h8 = lane & 8;
    double e = (h8 ? r3[1] : r3[0]) + __shfl_xor(h8 ? r3[0] : r3[1], 8);
    e += __shfl_xor(e, 16);
    e += __shfl_xor(e, 32);

    const int j = 8 * (lane & 1) + 4 * ((lane >> 1) & 1) +
                  2 * ((lane >> 2) & 1) + ((lane >> 3) & 1);
    if (lane < NC) {
        const float s = (e >= (double)thl[j]) ? 1.0f : 0.0f;
        out[(size_t)b * N + n0 + j] = s;   // 16 dwords in 64 B: one transaction
        s_cnt[g][j] = s;
    }
    __syncthreads();
    if (tid < NC) {
        // Plain store; visibility to k2 guaranteed by the kernel boundary.
        float c = 0.0f;
        #pragma unroll
        for (int k = 0; k < BQ; ++k) c += s_cnt[k][tid];
        partial[(size_t)bq * N + n0 + tid] = c;
    }
}

// Kernel 2: thread per neuron; sum 16 group-partials (coalesced), emit epilogue.
__global__ __launch_bounds__(256) void mpjrd_finalize_kernel(
    const float* __restrict__ partial,
    const float* __restrict__ theta,
    const float* __restrict__ r_hat,
    float*       __restrict__ out)
{
    const int n = blockIdx.x * 256 + threadIdx.x;
    float c = 0.0f;
    #pragma unroll
    for (int i = 0; i < NBQ; ++i) c += partial[(size_t)i * N + n];
    const float rate = c * (1.0f / 128.0f);
    const float rh   = 0.95f * r_hat[n] + 0.05f * rate;  // (1-ALPHA)*r_hat + ALPHA*rate
    const float th   = theta[n] + 0.1f * (rh - 0.1f);    // theta + THETA_LR*(rh - R_TARGET)
    out[(size_t)B * N + n]         = rate;
    out[(size_t)B * N + N + n]     = th;
    out[(size_t)B * N + 2 * N + n] = rh;
}

extern "C" void kernel_launch(void* const* d_in, const int* in_sizes, int n_in,
                              void* d_out, int out_size, void* d_ws, size_t ws_size,
                              hipStream_t stream) {
    const float* x     = (const float*)d_in[0];
    const float* W     = (const float*)d_in[1];
    const float* theta = (const float*)d_in[2];
    const float* r_hat = (const float*)d_in[3];
    float* out     = (float*)d_out;
    float* partial = (float*)d_ws;   // NBQ*N floats = 64 KB, fully written each call

    mpjrd_spike_kernel<<<NBQ * NCH, 512, 0, stream>>>(x, W, theta, out, partial);
    mpjrd_finalize_kernel<<<N / 256, 256, 0, stream>>>(partial, theta, r_hat, out);
}

// Round 12
// 45.763 us; speedup vs baseline: 1.0450x; 1.0174x over previous
//
#include <hip/hip_runtime.h>

// Problem constants: B=128, N=1024, D=8, S=64
constexpr int B   = 128;
constexpr int N   = 1024;
constexpr int DS  = 512;            // D*S, contiguous innermost per (b,n)
constexpr int NC  = 16;             // n-chunk per block (measured optimum)
constexpr int NCH = N / NC;         // 64 chunks
constexpr int BQ  = 4;              // b's per block (one per wave; measured optimum)
constexpr int NBQ = B / BQ;         // 32 b-quads

typedef float f32x4 __attribute__((ext_vector_type(4)));

// FINAL = R9, the measured optimum of the explored design space:
//   contiguity ladder: 2KB run -, 16KB +4% (R3), 32KB +2.5% (R9), 64KB -4.5% (R10);
//   block shape: BQ=4 (256 thr) > BQ=8 (512 thr, R11 -1.8%: wider barrier convoy);
//   fusion: 2-kernel beats fused handshake (R7 +8us) and fences (R6 +16x);
//   fp64 dot accumulation -> threshold decisions bit-stable vs numpy (absmax 0.0, R1-R11).
// k1 = 256 MB x-stream at ~5.9 TB/s ~= 94% of the measured 6.29 TB/s read
// ceiling (m13); k2+gap ~2.4us. Structural floor ~43us; this kernel: ~45.7us.
__global__ __launch_bounds__(256) void mpjrd_spike_kernel(
    const float* __restrict__ x,       // [B,N,DS]
    const float* __restrict__ W,       // [N,DS]
    const float* __restrict__ theta,   // [N]
    float*       __restrict__ out,     // spikes[B,N] | rates[N] | thetas[N] | r_hats[N]
    float*       __restrict__ partial) // ws: [NBQ][N]
{
    __shared__ float Wl[NC * DS];      // 32 KB W tile
    __shared__ float thl[NC];
    __shared__ float s_cnt[BQ][NC];

    const int tid  = threadIdx.x;
    const int lane = tid & 63;
    const int g    = tid >> 6;                 // wave in block = b within quad
    const int nc   = blockIdx.x & (NCH - 1);
    const int bq   = blockIdx.x >> 6;          // blockIdx / NCH
    const int n0   = nc * NC;
    const int b    = bq * BQ + g;

    // Stage W tile: 8192 floats = 2048 float4, 8 per thread, coalesced.
    {
        const f32x4* Wg = reinterpret_cast<const f32x4*>(W + (size_t)n0 * DS);
        f32x4* Wd = reinterpret_cast<f32x4*>(Wl);
        #pragma unroll
        for (int r = 0; r < 8; ++r) Wd[tid + r * 256] = Wg[tid + r * 256];
        if (tid < NC) thl[tid] = theta[n0 + tid];
    }
    __syncthreads();

    const float* xp0 = x + ((size_t)b * N + n0) * DS + (size_t)lane * 4;

    // 16 per-lane fp64 partial dots; no cross-lane ops in the streaming loop.
    double a[NC];
    #pragma unroll
    for (int j = 0; j < NC; ++j) {
        const float* xp = xp0 + (size_t)j * DS;
        const f32x4 x0 = __builtin_nontemporal_load(reinterpret_cast<const f32x4*>(xp));
        const f32x4 x1 = __builtin_nontemporal_load(reinterpret_cast<const f32x4*>(xp + 256));
        const f32x4 wa = *reinterpret_cast<const f32x4*>(Wl + j * DS + lane * 4);
        const f32x4 wb = *reinterpret_cast<const f32x4*>(Wl + j * DS + lane * 4 + 256);
        // fp64 accumulation: fp32*fp32 exact in fp64 -> threshold decisions
        // bit-stable vs the numpy reference (spikes absmax 0.0 in R1-R11).
        double p0 = (double)x0.x * (double)wa.x;
        p0 += (double)x0.y * (double)wa.y;
        p0 += (double)x0.z * (double)wa.z;
        p0 += (double)x0.w * (double)wa.w;
        double p1 = (double)x1.x * (double)wb.x;
        p1 += (double)x1.y * (double)wb.y;
        p1 += (double)x1.z * (double)wb.z;
        p1 += (double)x1.w * (double)wb.w;
        a[j] = p0 + p1;
    }

    // Joint reduce-scatter: 64 lanes x 16 values -> lane (l&15) owns
    // j = 8*(l&1) + 4*((l>>1)&1) + 2*((l>>2)&1) + ((l>>3)&1).
    const bool h1 = lane & 1;
    double r1[8];
    #pragma unroll
    for (int k = 0; k < 8; ++k)
        r1[k] = (h1 ? a[k + 8] : a[k]) + __shfl_xor(h1 ? a[k] : a[k + 8], 1);
    const bool h2 = lane & 2;
    double r2[4];
    #pragma unroll
    for (int k = 0; k < 4; ++k)
        r2[k] = (h2 ? r1[k + 4] : r1[k]) + __shfl_xor(h2 ? r1[k] : r1[k + 4], 2);
    const bool h4 = lane & 4;
    double r3[2];
    #pragma unroll
    for (int k = 0; k < 2; ++k)
        r3[k] = (h4 ? r2[k + 2] : r2[k]) + __shfl_xor(h4 ? r2[k] : r2[k + 2], 4);
    const bool h8 = lane & 8;
    double e = (h8 ? r3[1] : r3[0]) + __shfl_xor(h8 ? r3[0] : r3[1], 8);
    e += __shfl_xor(e, 16);
    e += __shfl_xor(e, 32);

    const int j = 8 * (lane & 1) + 4 * ((lane >> 1) & 1) +
                  2 * ((lane >> 2) & 1) + ((lane >> 3) & 1);
    if (lane < NC) {
        const float s = (e >= (double)thl[j]) ? 1.0f : 0.0f;
        out[(size_t)b * N + n0 + j] = s;   // 16 dwords in 64 B: one transaction
        s_cnt[g][j] = s;
    }
    __syncthreads();
    if (tid < NC) {
        // Plain store; visibility to k2 guaranteed by the kernel boundary.
        partial[(size_t)bq * N + n0 + tid] =
            s_cnt[0][tid] + s_cnt[1][tid] + s_cnt[2][tid] + s_cnt[3][tid];
    }
}

// Kernel 2: thread per neuron; sum 32 quad-partials (coalesced), emit epilogue.
__global__ __launch_bounds__(256) void mpjrd_finalize_kernel(
    const float* __restrict__ partial,
    const float* __restrict__ theta,
    const float* __restrict__ r_hat,
    float*       __restrict__ out)
{
    const int n = blockIdx.x * 256 + threadIdx.x;
    float c = 0.0f;
    #pragma unroll
    for (int i = 0; i < NBQ; ++i) c += partial[(size_t)i * N + n];
    const float rate = c * (1.0f / 128.0f);
    const float rh   = 0.95f * r_hat[n] + 0.05f * rate;  // (1-ALPHA)*r_hat + ALPHA*rate
    const float th   = theta[n] + 0.1f * (rh - 0.1f);    // theta + THETA_LR*(rh - R_TARGET)
    out[(size_t)B * N + n]         = rate;
    out[(size_t)B * N + N + n]     = th;
    out[(size_t)B * N + 2 * N + n] = rh;
}

extern "C" void kernel_launch(void* const* d_in, const int* in_sizes, int n_in,
                              void* d_out, int out_size, void* d_ws, size_t ws_size,
                              hipStream_t stream) {
    const float* x     = (const float*)d_in[0];
    const float* W     = (const float*)d_in[1];
    const float* theta = (const float*)d_in[2];
    const float* r_hat = (const float*)d_in[3];
    float* out     = (float*)d_out;
    float* partial = (float*)d_ws;   // NBQ*N floats = 128 KB, fully written each call

    mpjrd_spike_kernel<<<NBQ * NCH, 256, 0, stream>>>(x, W, theta, out, partial);
    mpjrd_finalize_kernel<<<N / 256, 256, 0, stream>>>(partial, theta, r_hat, out);
}